// Round 16
// baseline (52.761 us; speedup 1.0000x reference)
//
#include <hip/hip_runtime.h>
#include <hip/hip_bf16.h>

// SimilarityLayer: out[e,q,w,n,m] = <p[e,w,:,n], q[e,q,:,m]> / (|p||q| + 1e-8)
// E=8 W=5 C=640 N=49 Q=75.
// R16: kill the per-chunk barrier cadence (R9/R12/R15 invariant wall).
//      One block per (e,q), 512 thr: stage the WHOLE query slice (20 chunks)
//      bf16-fragment-ordered into 80KB LDS in one deeply-pipelined burst
//      (each thread 10 granules, 2-deep NAMED regs -- R15's spill-proof
//      pattern), ONE __syncthreads, then a BARRIER-FREE K-loop: per wave/chunk
//      {2 A-frag b128 from aimg (L2-hot) + 4 ds_read_b128 + 8 MFMA}.
//      R8 evidence: this pure-consumer loop runs ~10us when fed (gemm2).

#define E_CNT 8
#define W_CNT 5
#define C_CNT 640
#define N_CNT 49
#define Q_CNT 75
#define MROWS 245                    // W*N
#define NC32 20                      // K chunks of 32
#define AFRAG_CH 16384               // per (e,chunk): 16 row-tiles x 64 lanes x 16B
#define AIMG_E (NC32 * AFRAG_CH)     // 327,680 B per e
#define AIMG_SIZE (E_CNT * AIMG_E)   // 2,621,440
#define PN_OFF AIMG_SIZE
#define PN_BYTES (E_CNT * 10 * MROWS * 4)
#define WS1 ((size_t)(PN_OFF + PN_BYTES))

typedef __attribute__((ext_vector_type(8))) short bf16x8;
typedef __attribute__((ext_vector_type(4))) float f32x4;

static __device__ __forceinline__ short f2bf(float f) {
    __hip_bfloat16 h = __float2bfloat16(f);
    return *reinterpret_cast<short*>(&h);
}

// ---------------- prep_a: proto -> fragment-ordered bf16 A image + partials --
__global__ __launch_bounds__(256, 4)
void prep_a_kernel(const float* __restrict__ proto,
                   unsigned char* __restrict__ aimg,
                   float* __restrict__ pn_part)
{
    __shared__ float pns[MROWS];
    const int b = blockIdx.x;            // 80 = e*10 + c64
    const int e = b / 10, c64 = b % 10;
    const float* pbase = proto + (size_t)e * (W_CNT * C_CNT * N_CNT);
    unsigned char* ebase = aimg + (size_t)e * AIMG_E;
    const int t = threadIdx.x;
    if (t < MROWS) pns[t] = 0.f;
    __syncthreads();

    #pragma unroll
    for (int i = 0; i < 8; ++i) {
        const int s = t + i * 256;       // slot = kb*245 + nw, kb in [0,8)
        int nw, kb;
        bf16x8 pk;
        if (s < 8 * MROWS) {
            kb = s / MROWS;
            nw = s - kb * MROWS;
            const int w = nw / N_CNT, n = nw - w * N_CNT;
            const float* g = pbase + ((size_t)(w * C_CNT + c64 * 64 + kb * 8)) * N_CNT + n;
            float ss = 0.f;
            #pragma unroll
            for (int j = 0; j < 8; ++j) {
                const float f = g[(size_t)j * N_CNT];
                ss += f * f;
                pk[j] = f2bf(f);
            }
            atomicAdd(&pns[nw], ss);
        } else {
            const int x = s - 8 * MROWS; // zero-pad rows 245..255
            nw = MROWS + (x >> 3);
            kb = x & 7;
            pk = (bf16x8){0, 0, 0, 0, 0, 0, 0, 0};
        }
        const int c32 = c64 * 2 + (kb >> 2);
        const int ln2 = ((kb & 3) << 4) | (nw & 15);
        *reinterpret_cast<bf16x8*>(
            ebase + (size_t)c32 * AFRAG_CH + (size_t)((nw >> 4) * 64 + ln2) * 16) = pk;
    }
    __syncthreads();
    if (t < MROWS) pn_part[(size_t)(e * 10 + c64) * MROWS + t] = pns[t];
}

// ---------------- gemm10: stage-once LDS B + barrier-free K-loop -------------
__global__ __launch_bounds__(512, 2)
void gemm10_kernel(const float* __restrict__ query,
                   const unsigned char* __restrict__ aimg,
                   const float* __restrict__ pn_part,
                   float* __restrict__ out)
{
    __shared__ __align__(16) unsigned char Ball[NC32 * 4096];  // 80 KB: all B frags
    __shared__ float qn[64];
    __shared__ float pnl[256];

    const int b = blockIdx.x;            // 600
    const int e = b & 7;                 // same e -> same XCD -> aimg L2-hot
    const int q = b >> 3;
    const int eq = e * Q_CNT + q;
    const int t = threadIdx.x;
    const int wv = t >> 6, ln = t & 63;
    const int lrow = ln & 15, lk = ln >> 4;

    const float* __restrict__ qsl = query + (size_t)eq * (C_CNT * N_CNT);

    // ---- staging assignment: slot = t&255 -> granule (fjS, lnS); par = t>>8
    //      thread stages chunks par, par+2, ..., par+18 (10 granules)
    const int slot = t & 255;
    const int par  = t >> 8;             // 0 or 1
    const int fjS  = slot >> 6;          // 0..3
    const int lnS  = slot & 63;
    const int col  = fjS * 16 + (slot & 15);
    const int colc = (col < N_CNT) ? col : (N_CNT - 1);
    const int lkS  = (slot >> 4) & 3;
    const float* __restrict__ sbase = qsl + (size_t)(lkS * 8) * N_CNT + colc;
    const int swoff = fjS * 1024 + lnS * 16;

    // ---- compute role: wave wv owns rows [wv*32,+32) = row-tiles wv*2+{0,1}
    const unsigned char* __restrict__ abase =
        aimg + (size_t)e * AIMG_E + (size_t)((wv * 2) * 64 + ln) * 16;

    // init norms
    if (t < 64) qn[t] = 0.f;
    if (t < MROWS) {
        float s = 0.f;
        #pragma unroll
        for (int cc = 0; cc < 10; ++cc)
            s += pn_part[(size_t)(e * 10 + cc) * MROWS + t];
        pnl[t] = sqrtf(s);
    }
    __syncthreads();                     // qn zeroed before any atomicAdd

    // ---- stage ALL 10 chunks (this thread's parity), 2-deep named pipeline --
    float sA0, sA1, sA2, sA3, sA4, sA5, sA6, sA7;
    float sB0, sB1, sB2, sB3, sB4, sB5, sB6, sB7;
    float ssq = 0.f;

#define SLOAD_A(c) do {                                                         \
    const float* p_ = sbase + (size_t)((c) * 32) * N_CNT;                       \
    sA0 = p_[0];          sA1 = p_[1 * N_CNT];                                  \
    sA2 = p_[2 * N_CNT];  sA3 = p_[3 * N_CNT];                                  \
    sA4 = p_[4 * N_CNT];  sA5 = p_[5 * N_CNT];                                  \
    sA6 = p_[6 * N_CNT];  sA7 = p_[7 * N_CNT];                                  \
} while (0)

#define SLOAD_B(c) do {                                                         \
    const float* p_ = sbase + (size_t)((c) * 32) * N_CNT;                       \
    sB0 = p_[0];          sB1 = p_[1 * N_CNT];                                  \
    sB2 = p_[2 * N_CNT];  sB3 = p_[3 * N_CNT];                                  \
    sB4 = p_[4 * N_CNT];  sB5 = p_[5 * N_CNT];                                  \
    sB6 = p_[6 * N_CNT];  sB7 = p_[7 * N_CNT];                                  \
} while (0)

#define SPROC_A(c) do {                                                         \
    bf16x8 pk_;                                                                 \
    ssq += sA0*sA0 + sA1*sA1 + sA2*sA2 + sA3*sA3                                \
         + sA4*sA4 + sA5*sA5 + sA6*sA6 + sA7*sA7;                               \
    pk_[0]=f2bf(sA0); pk_[1]=f2bf(sA1); pk_[2]=f2bf(sA2); pk_[3]=f2bf(sA3);     \
    pk_[4]=f2bf(sA4); pk_[5]=f2bf(sA5); pk_[6]=f2bf(sA6); pk_[7]=f2bf(sA7);     \
    *reinterpret_cast<bf16x8*>(Ball + (c) * 4096 + swoff) = pk_;                \
} while (0)

#define SPROC_B(c) do {                                                         \
    bf16x8 pk_;                                                                 \
    ssq += sB0*sB0 + sB1*sB1 + sB2*sB2 + sB3*sB3                                \
         + sB4*sB4 + sB5*sB5 + sB6*sB6 + sB7*sB7;                               \
    pk_[0]=f2bf(sB0); pk_[1]=f2bf(sB1); pk_[2]=f2bf(sB2); pk_[3]=f2bf(sB3);     \
    pk_[4]=f2bf(sB4); pk_[5]=f2bf(sB5); pk_[6]=f2bf(sB6); pk_[7]=f2bf(sB7);     \
    *reinterpret_cast<bf16x8*>(Ball + (c) * 4096 + swoff) = pk_;                \
} while (0)

    SLOAD_A(par);
    SLOAD_B(par + 2);
    SPROC_A(par);
    SLOAD_A(par + 4);
    SPROC_B(par + 2);
    SLOAD_B(par + 6);
    SPROC_A(par + 4);
    SLOAD_A(par + 8);
    SPROC_B(par + 6);
    SLOAD_B(par + 10);
    SPROC_A(par + 8);
    SLOAD_A(par + 12);
    SPROC_B(par + 10);
    SLOAD_B(par + 14);
    SPROC_A(par + 12);
    SLOAD_A(par + 16);
    SPROC_B(par + 14);
    SLOAD_B(par + 18);
    SPROC_A(par + 16);
    SPROC_B(par + 18);

    atomicAdd(&qn[col], ssq);            // garbage at col>=49 via clamp: unused
    __syncthreads();                     // THE one barrier: LDS B + qn ready

    // ---- barrier-free K-loop ----
    bf16x8 afrA0, afrA1, afrB0, afrB1;
    f32x4 acc[2][4];
    #pragma unroll
    for (int i = 0; i < 2; ++i)
        #pragma unroll
        for (int j = 0; j < 4; ++j) acc[i][j] = (f32x4){0.f, 0.f, 0.f, 0.f};

#define AISSUE_A(c) do {                                                        \
    afrA0 = *reinterpret_cast<const bf16x8*>(abase + (size_t)(c) * AFRAG_CH);   \
    afrA1 = *reinterpret_cast<const bf16x8*>(abase + (size_t)(c) * AFRAG_CH + 1024); \
} while (0)

#define AISSUE_B(c) do {                                                        \
    afrB0 = *reinterpret_cast<const bf16x8*>(abase + (size_t)(c) * AFRAG_CH);   \
    afrB1 = *reinterpret_cast<const bf16x8*>(abase + (size_t)(c) * AFRAG_CH + 1024); \
} while (0)

#define DO_MFMA(c, a0, a1) do {                                                 \
    const unsigned char* bb_ = Ball + (c) * 4096;                               \
    bf16x8 bfr0_ = *reinterpret_cast<const bf16x8*>(bb_ + 0 * 1024 + ln * 16);  \
    bf16x8 bfr1_ = *reinterpret_cast<const bf16x8*>(bb_ + 1 * 1024 + ln * 16);  \
    bf16x8 bfr2_ = *reinterpret_cast<const bf16x8*>(bb_ + 2 * 1024 + ln * 16);  \
    bf16x8 bfr3_ = *reinterpret_cast<const bf16x8*>(bb_ + 3 * 1024 + ln * 16);  \
    acc[0][0] = __builtin_amdgcn_mfma_f32_16x16x32_bf16(a0, bfr0_, acc[0][0], 0, 0, 0); \
    acc[0][1] = __builtin_amdgcn_mfma_f32_16x16x32_bf16(a0, bfr1_, acc[0][1], 0, 0, 0); \
    acc[0][2] = __builtin_amdgcn_mfma_f32_16x16x32_bf16(a0, bfr2_, acc[0][2], 0, 0, 0); \
    acc[0][3] = __builtin_amdgcn_mfma_f32_16x16x32_bf16(a0, bfr3_, acc[0][3], 0, 0, 0); \
    acc[1][0] = __builtin_amdgcn_mfma_f32_16x16x32_bf16(a1, bfr0_, acc[1][0], 0, 0, 0); \
    acc[1][1] = __builtin_amdgcn_mfma_f32_16x16x32_bf16(a1, bfr1_, acc[1][1], 0, 0, 0); \
    acc[1][2] = __builtin_amdgcn_mfma_f32_16x16x32_bf16(a1, bfr2_, acc[1][2], 0, 0, 0); \
    acc[1][3] = __builtin_amdgcn_mfma_f32_16x16x32_bf16(a1, bfr3_, acc[1][3], 0, 0, 0); \
} while (0)

    AISSUE_A(0);
    for (int cc = 0; cc < NC32; cc += 2) {
        AISSUE_B(cc + 1);
        DO_MFMA(cc, afrA0, afrA1);
        if (cc + 2 < NC32) AISSUE_A(cc + 2);
        DO_MFMA(cc + 1, afrB0, afrB1);
    }

    // ---- epilogue: row = wv*32 + fi*16 + lk*4 + rr ; col = fj*16 + lrow ----
    float nq4[4];
    #pragma unroll
    for (int fj = 0; fj < 4; ++fj) {
        const int m = fj * 16 + lrow;
        nq4[fj] = (m < N_CNT) ? sqrtf(qn[m]) : 1.f;
    }
    float* __restrict__ osl = out + (size_t)eq * (W_CNT * N_CNT * N_CNT);
    #pragma unroll
    for (int fi = 0; fi < 2; ++fi) {
        #pragma unroll
        for (int rr = 0; rr < 4; ++rr) {
            const int row = wv * 32 + fi * 16 + lk * 4 + rr;
            if (row < MROWS) {
                const float np_ = pnl[row];
                #pragma unroll
                for (int fj = 0; fj < 4; ++fj) {
                    const int m = fj * 16 + lrow;
                    if (m < N_CNT) {
                        const float den = np_ * nq4[fj] + 1e-8f;
                        osl[row * N_CNT + m] = acc[fi][fj][rr] * __builtin_amdgcn_rcpf(den);
                    }
                }
            }
        }
    }
#undef SLOAD_A
#undef SLOAD_B
#undef SPROC_A
#undef SPROC_B
#undef AISSUE_A
#undef AISSUE_B
#undef DO_MFMA
}

// ---------------- tier-0 fallback (R2 kernel, no ws) -------------------------
struct SMemFB {
    unsigned char A[256 * 128];
    unsigned char B[64 * 128];
    float ns[320];
};

__global__ __launch_bounds__(512, 4)
void sim_fallback_kernel(const float* __restrict__ proto,
                         const float* __restrict__ query,
                         float* __restrict__ out)
{
    __shared__ SMemFB smf;
    const int t = threadIdx.x;
    const int e = blockIdx.x / Q_CNT;
    const int q = blockIdx.x - e * Q_CNT;
    const float* pbase = proto + (size_t)e * (W_CNT * C_CNT * N_CNT);
    const float* qbase = query + ((size_t)e * Q_CNT + q) * (C_CNT * N_CNT);
    unsigned char* lds = (unsigned char*)&smf;
    if (t < 320) smf.ns[t] = 0.f;
    if (t < 208) {
        if (t < 88) *reinterpret_cast<f32x4*>(smf.A + 245 * 128 + t * 16) = (f32x4){0.f,0.f,0.f,0.f};
        else        *reinterpret_cast<f32x4*>(smf.B + 49 * 128 + (t - 88) * 16) = (f32x4){0.f,0.f,0.f,0.f};
    }
    const int nslot5 = (t < 304);
    const float* gp[5];
    int offidx[5];
    #pragma unroll
    for (int i = 0; i < 5; ++i) {
        gp[i] = pbase; offidx[i] = 0;
        if (i < 4 || nslot5) {
            const int s = t + i * 512;
            if (s < 1960) {
                const int kb = s / 245, nw = s - kb * 245;
                const int w = nw / 49, n = nw - w * 49;
                gp[i] = pbase + ((size_t)w * C_CNT + kb * 8) * N_CNT + n;
                offidx[i] = (nw * 128 + ((kb ^ (nw & 7)) << 4)) | (nw << 16);
            } else {
                const int s2 = s - 1960;
                const int kb = s2 / 49, mq = s2 - kb * 49;
                gp[i] = qbase + (size_t)(kb * 8) * N_CNT + mq;
                offidx[i] = (32768 + mq * 128 + ((kb ^ (mq & 7)) << 4)) | ((256 + mq) << 16);
            }
        }
    }
    float v[5][8];
    float ss[5] = {0.f,0.f,0.f,0.f,0.f};
    #pragma unroll
    for (int i = 0; i < 4; ++i)
        #pragma unroll
        for (int j = 0; j < 8; ++j) v[i][j] = gp[i][(size_t)j * N_CNT];
    if (nslot5)
        #pragma unroll
        for (int j = 0; j < 8; ++j) v[4][j] = gp[4][(size_t)j * N_CNT];
    f32x4 acc[2][4];
    #pragma unroll
    for (int i = 0; i < 2; ++i)
        #pragma unroll
        for (int j = 0; j < 4; ++j) acc[i][j] = (f32x4){0.f,0.f,0.f,0.f};
    const int wv = t >> 6, ln = t & 63, lrow = ln & 15, lk = ln >> 4;
    for (int kc = 0; kc < 10; ++kc) {
        #pragma unroll
        for (int i = 0; i < 5; ++i) {
            if (i < 4 || nslot5) {
                bf16x8 pk; float s8 = 0.f;
                #pragma unroll
                for (int j = 0; j < 8; ++j) { const float f = v[i][j]; s8 += f*f; pk[j] = f2bf(f); }
                ss[i] += s8;
                *reinterpret_cast<bf16x8*>(lds + (offidx[i] & 0xFFFF)) = pk;
            }
        }
        __syncthreads();
        if (kc < 9) {
            #pragma unroll
            for (int i = 0; i < 4; ++i) {
                gp[i] += 64 * N_CNT;
                #pragma unroll
                for (int j = 0; j < 8; ++j) v[i][j] = gp[i][(size_t)j * N_CNT];
            }
            if (nslot5) {
                gp[4] += 64 * N_CNT;
                #pragma unroll
                for (int j = 0; j < 8; ++j) v[4][j] = gp[4][(size_t)j * N_CNT];
            }
        }
        #pragma unroll
        for (int ks = 0; ks < 2; ++ks) {
            bf16x8 af[2], bfr[4];
            #pragma unroll
            for (int i = 0; i < 2; ++i) {
                const int row = (wv * 2 + i) * 16 + lrow;
                const int gr = (ks * 4 + lk) ^ (row & 7);
                af[i] = *reinterpret_cast<const bf16x8*>(lds + row * 128 + gr * 16);
            }
            #pragma unroll
            for (int j = 0; j < 4; ++j) {
                const int mq = j * 16 + lrow;
                const int gr = (ks * 4 + lk) ^ (mq & 7);
                bfr[j] = *reinterpret_cast<const bf16x8*>(lds + 32768 + mq * 128 + gr * 16);
            }
            #pragma unroll
            for (int i = 0; i < 2; ++i)
                #pragma unroll
                for (int j = 0; j < 4; ++j)
                    acc[i][j] = __builtin_amdgcn_mfma_f32_16x16x32_bf16(af[i], bfr[j], acc[i][j], 0, 0, 0);
        }
        __syncthreads();
    }
    #pragma unroll
    for (int i = 0; i < 5; ++i)
        if (i < 4 || nslot5) atomicAdd(&smf.ns[offidx[i] >> 16], ss[i]);
    __syncthreads();
    float nq[4];
    #pragma unroll
    for (int j = 0; j < 4; ++j) {
        const int mq = j * 16 + lrow;
        nq[j] = (mq < N_CNT) ? sqrtf(smf.ns[256 + mq]) : 1.f;
    }
    float* obase = out + (size_t)(e * Q_CNT + q) * (W_CNT * N_CNT * N_CNT);
    #pragma unroll
    for (int i = 0; i < 2; ++i) {
        #pragma unroll
        for (int rr = 0; rr < 4; ++rr) {
            const int nw = (wv * 2 + i) * 16 + lk * 4 + rr;
            if (nw < W_CNT * N_CNT) {
                const int w = nw / 49, n = nw - w * 49;
                const float np_ = sqrtf(smf.ns[nw]);
                float* orow = obase + ((size_t)w * N_CNT + n) * N_CNT;
                #pragma unroll
                for (int j = 0; j < 4; ++j) {
                    const int mq = j * 16 + lrow;
                    if (mq < N_CNT) orow[mq] = acc[i][j][rr] / (np_ * nq[j] + 1e-8f);
                }
            }
        }
    }
}

extern "C" void kernel_launch(void* const* d_in, const int* in_sizes, int n_in,
                              void* d_out, int out_size, void* d_ws, size_t ws_size,
                              hipStream_t stream)
{
    const float* proto = (const float*)d_in[0];
    const float* query = (const float*)d_in[1];
    float* out = (float*)d_out;

    if (ws_size < WS1) {
        hipLaunchKernelGGL(sim_fallback_kernel, dim3(E_CNT * Q_CNT), dim3(512), 0, stream,
                           proto, query, out);
        return;
    }

    unsigned char* aimg = (unsigned char*)d_ws;
    float* pn_part = (float*)((unsigned char*)d_ws + PN_OFF);

    hipLaunchKernelGGL(prep_a_kernel, dim3(E_CNT * 10), dim3(256), 0, stream,
                       proto, aimg, pn_part);
    hipLaunchKernelGGL(gemm10_kernel, dim3(E_CNT * Q_CNT), dim3(512), 0, stream,
                       query, aimg, pn_part, out);
}

// Round 17
// 46.364 us; speedup vs baseline: 1.1380x; 1.1380x over previous
//
#include <hip/hip_runtime.h>
#include <hip/hip_bf16.h>

// SimilarityLayer: out[e,q,w,n,m] = <p[e,w,:,n], q[e,q,:,m]> / (|p||q| + 1e-8)
// E=8 W=5 C=640 N=49 Q=75.
// R17: R9/gemm6's winning geometry (1200 x 256thr, per-chunk lgkm barrier)
//      with the ONE unfixed component replaced: B staging VMEM. Was 8 strided
//      scalars/thread (~190 L1-line services/block-chunk); now 392 coalesced
//      float4 -> fp32 LDS (3-deep) -> 8 strided b32 LDS reads (2-way alias =
//      free) + cvt -> bf16 Bbuf (consumer unchanged). Named regs only
//      (spill-proof, R15 pattern); runtime loop; LDS runtime-indexed (legal).

#define E_CNT 8
#define W_CNT 5
#define C_CNT 640
#define N_CNT 49
#define Q_CNT 75
#define MROWS 245                    // W*N
#define NC32 20                      // K chunks of 32
#define CHF 1568                     // floats per B chunk (32 x 49)
#define AFRAG_CH 16384               // per (e,chunk): 16 row-tiles x 64 lanes x 16B
#define AIMG_E (NC32 * AFRAG_CH)     // 327,680 B per e
#define AIMG_SIZE (E_CNT * AIMG_E)   // 2,621,440
#define PN_OFF AIMG_SIZE
#define PN_BYTES (E_CNT * 10 * MROWS * 4)
#define WS1 ((size_t)(PN_OFF + PN_BYTES))

typedef __attribute__((ext_vector_type(8))) short bf16x8;
typedef __attribute__((ext_vector_type(4))) float f32x4;

static __device__ __forceinline__ short f2bf(float f) {
    __hip_bfloat16 h = __float2bfloat16(f);
    return *reinterpret_cast<short*>(&h);
}

// Barrier WITHOUT vmcnt drain: LDS visibility only; global loads stay in flight.
#define RAW_BARRIER() asm volatile("s_waitcnt lgkmcnt(0)\n\ts_barrier" ::: "memory")

// ---------------- prep_a: proto -> fragment-ordered bf16 A image + partials --
__global__ __launch_bounds__(256, 4)
void prep_a_kernel(const float* __restrict__ proto,
                   unsigned char* __restrict__ aimg,
                   float* __restrict__ pn_part)
{
    __shared__ float pns[MROWS];
    const int b = blockIdx.x;            // 80 = e*10 + c64
    const int e = b / 10, c64 = b % 10;
    const float* pbase = proto + (size_t)e * (W_CNT * C_CNT * N_CNT);
    unsigned char* ebase = aimg + (size_t)e * AIMG_E;
    const int t = threadIdx.x;
    if (t < MROWS) pns[t] = 0.f;
    __syncthreads();

    #pragma unroll
    for (int i = 0; i < 8; ++i) {
        const int s = t + i * 256;       // slot = kb*245 + nw, kb in [0,8)
        int nw, kb;
        bf16x8 pk;
        if (s < 8 * MROWS) {
            kb = s / MROWS;
            nw = s - kb * MROWS;
            const int w = nw / N_CNT, n = nw - w * N_CNT;
            const float* g = pbase + ((size_t)(w * C_CNT + c64 * 64 + kb * 8)) * N_CNT + n;
            float ss = 0.f;
            #pragma unroll
            for (int j = 0; j < 8; ++j) {
                const float f = g[(size_t)j * N_CNT];
                ss += f * f;
                pk[j] = f2bf(f);
            }
            atomicAdd(&pns[nw], ss);
        } else {
            const int x = s - 8 * MROWS; // zero-pad rows 245..255
            nw = MROWS + (x >> 3);
            kb = x & 7;
            pk = (bf16x8){0, 0, 0, 0, 0, 0, 0, 0};
        }
        const int c32 = c64 * 2 + (kb >> 2);
        const int ln2 = ((kb & 3) << 4) | (nw & 15);
        *reinterpret_cast<bf16x8*>(
            ebase + (size_t)c32 * AFRAG_CH + (size_t)((nw >> 4) * 64 + ln2) * 16) = pk;
    }
    __syncthreads();
    if (t < MROWS) pn_part[(size_t)(e * 10 + c64) * MROWS + t] = pns[t];
}

// ---------------- gemm11: R9 geometry + coalesced fp32-LDS B staging ---------
__global__ __launch_bounds__(256, 2)
void gemm11_kernel(const float* __restrict__ query,
                   const unsigned char* __restrict__ aimg,
                   const float* __restrict__ pn_part,
                   float* __restrict__ out)
{
    __shared__ __align__(16) float fbuf[3][CHF];            // fp32 chunks, 3-deep
    __shared__ __align__(16) unsigned char Bbuf[2 * 4096];  // bf16 frags, 2-deep
    __shared__ float qn[64];
    __shared__ float pnl[128];

    const int b = blockIdx.x;            // 1200
    const int e = b & 7;                 // same e -> same XCD -> aimg L2-hot
    const int mh = (b >> 3) & 1;         // M-half: rows [mh*128, +128)
    const int q = b >> 4;                // 0..74
    const int eq = e * Q_CNT + q;
    const int t = threadIdx.x;
    const int wv = t >> 6, ln = t & 63;
    const int lrow = ln & 15, lk = ln >> 4;

    const f32x4* __restrict__ qsl4 =
        reinterpret_cast<const f32x4*>(query + (size_t)eq * (C_CNT * N_CNT));

    // CVT role (all 256 threads): granule (fjS = t>>6, lnS = t&63)
    const int fjS = t >> 6;
    const int scol = fjS * 16 + (t & 15);
    const int scolc = (scol < N_CNT) ? scol : (N_CNT - 1);
    const int lkS = (t >> 4) & 3;
    const int swoff = fjS * 1024 + (t & 63) * 16;
    const int frd0 = lkS * 8 * N_CNT + scolc;   // fp32 LDS read base (words)

    // GLOAD role: vq0 = element t; vq1 = element 256+t (t<136)
    const bool t2 = t < (CHF / 4 - 256);

    // consumer: wave wv owns row-tiles mh*8 + wv*2 + {0,1}
    const unsigned char* __restrict__ abase =
        aimg + (size_t)e * AIMG_E + (size_t)((mh * 8 + wv * 2) * 64 + ln) * 16;

    if (t < 64) qn[t] = 0.f;
    if (t < 128) {
        const int row = mh * 128 + t;
        float s = 0.f;
        if (row < MROWS) {
            #pragma unroll
            for (int cc = 0; cc < 10; ++cc)
                s += pn_part[(size_t)(e * 10 + cc) * MROWS + row];
        }
        pnl[t] = sqrtf(s);
    }

    // named registers only (spill-proof)
    f32x4 vqA0, vqA1, vqB0, vqB1;
    bf16x8 afrA0, afrA1, afrB0, afrB1;
    f32x4 acc[2][4];
    #pragma unroll
    for (int i = 0; i < 2; ++i)
        #pragma unroll
        for (int j = 0; j < 4; ++j) acc[i][j] = (f32x4){0.f, 0.f, 0.f, 0.f};
    float ssq = 0.f;

#define GLOAD_A(c) do {                                                         \
    vqA0 = qsl4[(size_t)(c) * (CHF / 4) + t];                                   \
    if (t2) vqA1 = qsl4[(size_t)(c) * (CHF / 4) + 256 + t];                     \
} while (0)
#define GLOAD_B(c) do {                                                         \
    vqB0 = qsl4[(size_t)(c) * (CHF / 4) + t];                                   \
    if (t2) vqB1 = qsl4[(size_t)(c) * (CHF / 4) + 256 + t];                     \
} while (0)
#define FWRITE_A(c) do {                                                        \
    float* d_ = fbuf[(c) % 3];                                                  \
    *reinterpret_cast<f32x4*>(d_ + t * 4) = vqA0;                               \
    if (t2) *reinterpret_cast<f32x4*>(d_ + 1024 + t * 4) = vqA1;                \
} while (0)
#define FWRITE_B(c) do {                                                        \
    float* d_ = fbuf[(c) % 3];                                                  \
    *reinterpret_cast<f32x4*>(d_ + t * 4) = vqB0;                               \
    if (t2) *reinterpret_cast<f32x4*>(d_ + 1024 + t * 4) = vqB1;                \
} while (0)
#define CVT(c) do {                                                             \
    const float* f_ = fbuf[(c) % 3];                                            \
    float v0_ = f_[frd0];               float v1_ = f_[frd0 + 1 * N_CNT];       \
    float v2_ = f_[frd0 + 2 * N_CNT];   float v3_ = f_[frd0 + 3 * N_CNT];       \
    float v4_ = f_[frd0 + 4 * N_CNT];   float v5_ = f_[frd0 + 5 * N_CNT];       \
    float v6_ = f_[frd0 + 6 * N_CNT];   float v7_ = f_[frd0 + 7 * N_CNT];       \
    ssq += v0_*v0_ + v1_*v1_ + v2_*v2_ + v3_*v3_                                \
         + v4_*v4_ + v5_*v5_ + v6_*v6_ + v7_*v7_;                               \
    bf16x8 pk_;                                                                 \
    pk_[0]=f2bf(v0_); pk_[1]=f2bf(v1_); pk_[2]=f2bf(v2_); pk_[3]=f2bf(v3_);     \
    pk_[4]=f2bf(v4_); pk_[5]=f2bf(v5_); pk_[6]=f2bf(v6_); pk_[7]=f2bf(v7_);     \
    *reinterpret_cast<bf16x8*>(Bbuf + ((c) & 1) * 4096 + swoff) = pk_;          \
} while (0)
#define AISSUE_A(c) do {                                                        \
    afrA0 = *reinterpret_cast<const bf16x8*>(abase + (size_t)(c) * AFRAG_CH);   \
    afrA1 = *reinterpret_cast<const bf16x8*>(abase + (size_t)(c) * AFRAG_CH + 1024); \
} while (0)
#define AISSUE_B(c) do {                                                        \
    afrB0 = *reinterpret_cast<const bf16x8*>(abase + (size_t)(c) * AFRAG_CH);   \
    afrB1 = *reinterpret_cast<const bf16x8*>(abase + (size_t)(c) * AFRAG_CH + 1024); \
} while (0)
#define DO_MFMA(c, a0, a1) do {                                                 \
    const unsigned char* bb_ = Bbuf + ((c) & 1) * 4096;                         \
    bf16x8 bfr0_ = *reinterpret_cast<const bf16x8*>(bb_ + 0 * 1024 + ln * 16);  \
    bf16x8 bfr1_ = *reinterpret_cast<const bf16x8*>(bb_ + 1 * 1024 + ln * 16);  \
    bf16x8 bfr2_ = *reinterpret_cast<const bf16x8*>(bb_ + 2 * 1024 + ln * 16);  \
    bf16x8 bfr3_ = *reinterpret_cast<const bf16x8*>(bb_ + 3 * 1024 + ln * 16);  \
    acc[0][0] = __builtin_amdgcn_mfma_f32_16x16x32_bf16(a0, bfr0_, acc[0][0], 0, 0, 0); \
    acc[0][1] = __builtin_amdgcn_mfma_f32_16x16x32_bf16(a0, bfr1_, acc[0][1], 0, 0, 0); \
    acc[0][2] = __builtin_amdgcn_mfma_f32_16x16x32_bf16(a0, bfr2_, acc[0][2], 0, 0, 0); \
    acc[0][3] = __builtin_amdgcn_mfma_f32_16x16x32_bf16(a0, bfr3_, acc[0][3], 0, 0, 0); \
    acc[1][0] = __builtin_amdgcn_mfma_f32_16x16x32_bf16(a1, bfr0_, acc[1][0], 0, 0, 0); \
    acc[1][1] = __builtin_amdgcn_mfma_f32_16x16x32_bf16(a1, bfr1_, acc[1][1], 0, 0, 0); \
    acc[1][2] = __builtin_amdgcn_mfma_f32_16x16x32_bf16(a1, bfr2_, acc[1][2], 0, 0, 0); \
    acc[1][3] = __builtin_amdgcn_mfma_f32_16x16x32_bf16(a1, bfr3_, acc[1][3], 0, 0, 0); \
} while (0)

    // prologue
    GLOAD_A(0);                          // ch0 -> vqA
    GLOAD_B(1);                          // ch1 -> vqB
    FWRITE_A(0);                         // fbuf0
    AISSUE_A(0);
    RAW_BARRIER();                       // fbuf0 (+qn zero, pnl) visible
    CVT(0);                              // fbuf0 -> Bbuf0
    GLOAD_A(2);                          // ch2 -> vqA (freed by FWRITE_A(0))
    FWRITE_B(1);                         // fbuf1
    AISSUE_B(1);
    RAW_BARRIER();                       // Bbuf0 + fbuf1 visible

    for (int c = 0; c < NC32; ++c) {
        // GLOAD(c+3): parity (c+3)&1 -> opposite of c
        if (c + 3 < NC32) {
            if (c & 1) GLOAD_A(c + 3); else GLOAD_B(c + 3);
        }
        // FWRITE(c+2): parity (c+2)&1 == c&1
        if (c + 2 < NC32) {
            if (c & 1) FWRITE_B(c + 2); else FWRITE_A(c + 2);
        }
        // CVT(c+1): fbuf[(c+1)%3] -> Bbuf[(c+1)&1]
        if (c + 1 < NC32) CVT(c + 1);
        // MFMA(c) + A-frag reload for c+2 (same parity)
        if (c & 1) {
            DO_MFMA(c, afrB0, afrB1);
            if (c + 2 < NC32) AISSUE_B(c + 2);
        } else {
            DO_MFMA(c, afrA0, afrA1);
            if (c + 2 < NC32) AISSUE_A(c + 2);
        }
        if (c + 1 < NC32) RAW_BARRIER();
    }

    // ---- q-norms: reduce ssq over the 4 lk groups of each column ----
    {
        float s = ssq;
        s += __shfl_xor(s, 16);
        s += __shfl_xor(s, 32);
        if (lkS == 0) qn[fjS * 16 + (t & 15)] = s;
    }
    __syncthreads();

    // ---- epilogue: row = mh*128 + wv*32 + fi*16 + lk*4 + rr ; col = fj*16+lrow
    float nq4[4];
    #pragma unroll
    for (int fj = 0; fj < 4; ++fj) {
        const int m = fj * 16 + lrow;
        nq4[fj] = (m < N_CNT) ? sqrtf(qn[m]) : 1.f;
    }
    float* __restrict__ osl = out + (size_t)eq * (W_CNT * N_CNT * N_CNT);
    #pragma unroll
    for (int fi = 0; fi < 2; ++fi) {
        #pragma unroll
        for (int rr = 0; rr < 4; ++rr) {
            const int lr = wv * 32 + fi * 16 + lk * 4 + rr;
            const int row = mh * 128 + lr;
            if (row < MROWS) {
                const float np_ = pnl[lr];
                #pragma unroll
                for (int fj = 0; fj < 4; ++fj) {
                    const int m = fj * 16 + lrow;
                    if (m < N_CNT) {
                        const float den = np_ * nq4[fj] + 1e-8f;
                        osl[row * N_CNT + m] = acc[fi][fj][rr] * __builtin_amdgcn_rcpf(den);
                    }
                }
            }
        }
    }
#undef GLOAD_A
#undef GLOAD_B
#undef FWRITE_A
#undef FWRITE_B
#undef CVT
#undef AISSUE_A
#undef AISSUE_B
#undef DO_MFMA
}

// ---------------- tier-0 fallback (R2 kernel, no ws) -------------------------
struct SMemFB {
    unsigned char A[256 * 128];
    unsigned char B[64 * 128];
    float ns[320];
};

__global__ __launch_bounds__(512, 4)
void sim_fallback_kernel(const float* __restrict__ proto,
                         const float* __restrict__ query,
                         float* __restrict__ out)
{
    __shared__ SMemFB smf;
    const int t = threadIdx.x;
    const int e = blockIdx.x / Q_CNT;
    const int q = blockIdx.x - e * Q_CNT;
    const float* pbase = proto + (size_t)e * (W_CNT * C_CNT * N_CNT);
    const float* qbase = query + ((size_t)e * Q_CNT + q) * (C_CNT * N_CNT);
    unsigned char* lds = (unsigned char*)&smf;
    if (t < 320) smf.ns[t] = 0.f;
    if (t < 208) {
        if (t < 88) *reinterpret_cast<f32x4*>(smf.A + 245 * 128 + t * 16) = (f32x4){0.f,0.f,0.f,0.f};
        else        *reinterpret_cast<f32x4*>(smf.B + 49 * 128 + (t - 88) * 16) = (f32x4){0.f,0.f,0.f,0.f};
    }
    const int nslot5 = (t < 304);
    const float* gp[5];
    int offidx[5];
    #pragma unroll
    for (int i = 0; i < 5; ++i) {
        gp[i] = pbase; offidx[i] = 0;
        if (i < 4 || nslot5) {
            const int s = t + i * 512;
            if (s < 1960) {
                const int kb = s / 245, nw = s - kb * 245;
                const int w = nw / 49, n = nw - w * 49;
                gp[i] = pbase + ((size_t)w * C_CNT + kb * 8) * N_CNT + n;
                offidx[i] = (nw * 128 + ((kb ^ (nw & 7)) << 4)) | (nw << 16);
            } else {
                const int s2 = s - 1960;
                const int kb = s2 / 49, mq = s2 - kb * 49;
                gp[i] = qbase + (size_t)(kb * 8) * N_CNT + mq;
                offidx[i] = (32768 + mq * 128 + ((kb ^ (mq & 7)) << 4)) | ((256 + mq) << 16);
            }
        }
    }
    float v[5][8];
    float ss[5] = {0.f,0.f,0.f,0.f,0.f};
    #pragma unroll
    for (int i = 0; i < 4; ++i)
        #pragma unroll
        for (int j = 0; j < 8; ++j) v[i][j] = gp[i][(size_t)j * N_CNT];
    if (nslot5)
        #pragma unroll
        for (int j = 0; j < 8; ++j) v[4][j] = gp[4][(size_t)j * N_CNT];
    f32x4 acc[2][4];
    #pragma unroll
    for (int i = 0; i < 2; ++i)
        #pragma unroll
        for (int j = 0; j < 4; ++j) acc[i][j] = (f32x4){0.f,0.f,0.f,0.f};
    const int wv = t >> 6, ln = t & 63, lrow = ln & 15, lk = ln >> 4;
    for (int kc = 0; kc < 10; ++kc) {
        #pragma unroll
        for (int i = 0; i < 5; ++i) {
            if (i < 4 || nslot5) {
                bf16x8 pk; float s8 = 0.f;
                #pragma unroll
                for (int j = 0; j < 8; ++j) { const float f = v[i][j]; s8 += f*f; pk[j] = f2bf(f); }
                ss[i] += s8;
                *reinterpret_cast<bf16x8*>(lds + (offidx[i] & 0xFFFF)) = pk;
            }
        }
        __syncthreads();
        if (kc < 9) {
            #pragma unroll
            for (int i = 0; i < 4; ++i) {
                gp[i] += 64 * N_CNT;
                #pragma unroll
                for (int j = 0; j < 8; ++j) v[i][j] = gp[i][(size_t)j * N_CNT];
            }
            if (nslot5) {
                gp[4] += 64 * N_CNT;
                #pragma unroll
                for (int j = 0; j < 8; ++j) v[4][j] = gp[4][(size_t)j * N_CNT];
            }
        }
        #pragma unroll
        for (int ks = 0; ks < 2; ++ks) {
            bf16x8 af[2], bfr[4];
            #pragma unroll
            for (int i = 0; i < 2; ++i) {
                const int row = (wv * 2 + i) * 16 + lrow;
                const int gr = (ks * 4 + lk) ^ (row & 7);
                af[i] = *reinterpret_cast<const bf16x8*>(lds + row * 128 + gr * 16);
            }
            #pragma unroll
            for (int j = 0; j < 4; ++j) {
                const int mq = j * 16 + lrow;
                const int gr = (ks * 4 + lk) ^ (mq & 7);
                bfr[j] = *reinterpret_cast<const bf16x8*>(lds + 32768 + mq * 128 + gr * 16);
            }
            #pragma unroll
            for (int i = 0; i < 2; ++i)
                #pragma unroll
                for (int j = 0; j < 4; ++j)
                    acc[i][j] = __builtin_amdgcn_mfma_f32_16x16x32_bf16(af[i], bfr[j], acc[i][j], 0, 0, 0);
        }
        __syncthreads();
    }
    #pragma unroll
    for (int i = 0; i < 5; ++i)
        if (i < 4 || nslot5) atomicAdd(&smf.ns[offidx[i] >> 16], ss[i]);
    __syncthreads();
    float nq[4];
    #pragma unroll
    for (int j = 0; j < 4; ++j) {
        const int mq = j * 16 + lrow;
        nq[j] = (mq < N_CNT) ? sqrtf(smf.ns[256 + mq]) : 1.f;
    }
    float* obase = out + (size_t)(e * Q_CNT + q) * (W_CNT * N_CNT * N_CNT);
    #pragma unroll
    for (int i = 0; i < 2; ++i) {
        #pragma unroll
        for (int rr = 0; rr < 4; ++rr) {
            const int nw = (wv * 2 + i) * 16 + lk * 4 + rr;
            if (nw < W_CNT * N_CNT) {
                const int w = nw / 49, n = nw - w * 49;
                const float np_ = sqrtf(smf.ns[nw]);
                float* orow = obase + ((size_t)w * N_CNT + n) * N_CNT;
                #pragma unroll
                for (int j = 0; j < 4; ++j) {
                    const int mq = j * 16 + lrow;
                    if (mq < N_CNT) orow[mq] = acc[i][j][rr] / (np_ * nq[j] + 1e-8f);
                }
            }
        }
    }
}

extern "C" void kernel_launch(void* const* d_in, const int* in_sizes, int n_in,
                              void* d_out, int out_size, void* d_ws, size_t ws_size,
                              hipStream_t stream)
{
    const float* proto = (const float*)d_in[0];
    const float* query = (const float*)d_in[1];
    float* out = (float*)d_out;

    if (ws_size < WS1) {
        hipLaunchKernelGGL(sim_fallback_kernel, dim3(E_CNT * Q_CNT), dim3(512), 0, stream,
                           proto, query, out);
        return;
    }

    unsigned char* aimg = (unsigned char*)d_ws;
    float* pn_part = (float*)((unsigned char*)d_ws + PN_OFF);

    hipLaunchKernelGGL(prep_a_kernel, dim3(E_CNT * 10), dim3(256), 0, stream,
                       proto, aimg, pn_part);
    hipLaunchKernelGGL(gemm11_kernel, dim3(E_CNT * Q_CNT * 2), dim3(256), 0, stream,
                       query, aimg, pn_part, out);
}